// Round 4
// baseline (596.833 us; speedup 1.0000x reference)
//
#include <hip/hip_runtime.h>
#include <hip/hip_fp16.h>

#define EPS 1e-5f
#define SCAN_CHUNK 1024   // elements per block in the parallel scan

// ---------------- graph prep ----------------

__global__ __launch_bounds__(256) void hist_kernel(const int* __restrict__ ei, int E, int* __restrict__ count) {
    int e = blockIdx.x * blockDim.x + threadIdx.x;
    if (e < E) atomicAdd(&count[ei[E + e]], 1);   // col = target
}

__global__ __launch_bounds__(256) void dinv_kernel(const int* __restrict__ count, float* __restrict__ dinv, int n) {
    int i = blockIdx.x * blockDim.x + threadIdx.x;
    if (i < n) dinv[i] = rsqrtf((float)(count[i] + 1));   // +1 self-loop
}

// pass 1: per-block (1024 elems) local exclusive scan into rowptr, block total into bsum
__global__ __launch_bounds__(256) void scan_pass1(const int* __restrict__ count, int* __restrict__ rowptr,
                                                  int* __restrict__ bsum, int n) {
    __shared__ int ssum[256];
    int t = threadIdx.x;
    int base = blockIdx.x * SCAN_CHUNK + t * 4;
    int v0 = 0, v1 = 0, v2 = 0, v3 = 0;
    if (base + 3 < n) {
        int4 vv = *(const int4*)(count + base);
        v0 = vv.x; v1 = vv.y; v2 = vv.z; v3 = vv.w;
    } else {
        if (base + 0 < n) v0 = count[base + 0];
        if (base + 1 < n) v1 = count[base + 1];
        if (base + 2 < n) v2 = count[base + 2];
        if (base + 3 < n) v3 = count[base + 3];
    }
    int s = v0 + v1 + v2 + v3;
    ssum[t] = s;
    __syncthreads();
    for (int off = 1; off < 256; off <<= 1) {
        int u = (t >= off) ? ssum[t - off] : 0;
        __syncthreads();
        ssum[t] += u;
        __syncthreads();
    }
    int excl = ssum[t] - s;
    int p0 = excl, p1 = excl + v0, p2 = excl + v0 + v1, p3 = excl + v0 + v1 + v2;
    if (base + 3 < n) {
        *(int4*)(rowptr + base) = make_int4(p0, p1, p2, p3);
    } else {
        if (base + 0 < n) rowptr[base + 0] = p0;
        if (base + 1 < n) rowptr[base + 1] = p1;
        if (base + 2 < n) rowptr[base + 2] = p2;
        if (base + 3 < n) rowptr[base + 3] = p3;
    }
    if (t == 255) bsum[blockIdx.x] = ssum[255];
}

// pass 2: scan block sums (nb <= 1024), write exclusive block offsets + rowptr[n]
__global__ __launch_bounds__(1024) void scan_pass2(const int* __restrict__ bsum, int* __restrict__ boffs,
                                                   int* __restrict__ rowptr, int nb, int n) {
    __shared__ int s[1024];
    int t = threadIdx.x;
    int v = (t < nb) ? bsum[t] : 0;
    s[t] = v;
    __syncthreads();
    for (int off = 1; off < 1024; off <<= 1) {
        int u = (t >= off) ? s[t - off] : 0;
        __syncthreads();
        s[t] += u;
        __syncthreads();
    }
    if (t < nb) boffs[t] = s[t] - v;
    if (t == 1023) rowptr[n] = s[1023];
}

// pass 3: add block offsets, materialize cursor
__global__ __launch_bounds__(256) void scan_pass3(int* __restrict__ rowptr, int* __restrict__ cursor,
                                                  const int* __restrict__ boffs, int n) {
    int t = threadIdx.x;
    int base = blockIdx.x * SCAN_CHUNK + t * 4;
    int off = boffs[blockIdx.x];
    if (base + 3 < n) {
        int4 v = *(int4*)(rowptr + base);
        v.x += off; v.y += off; v.z += off; v.w += off;
        *(int4*)(rowptr + base) = v;
        *(int4*)(cursor + base) = v;
    } else {
        for (int j = 0; j < 4; ++j)
            if (base + j < n) { int v = rowptr[base + j] + off; rowptr[base + j] = v; cursor[base + j] = v; }
    }
}

// scatter: CSR entry = (source index, norm weight dinv[src]*dinv[dst]) packed as int2
__global__ __launch_bounds__(256) void scatter_kernel(const int* __restrict__ ei, int E,
                                                      const float* __restrict__ dinv,
                                                      int* __restrict__ cursor, int2* __restrict__ csrw) {
    int e = blockIdx.x * blockDim.x + threadIdx.x;
    if (e < E) {
        int r = ei[e];          // source
        int c = ei[E + e];      // target
        int pos = atomicAdd(&cursor[c], 1);
        float w = dinv[r] * dinv[c];
        csrw[pos] = make_int2(r, __float_as_int(w));
    }
}

// ---------------- dense GEMM: [n,K](f32) @ [K,64](f32) -> [n,64] (f16) ----------------
// 32 rows/block; inner loop k-step-4: A via broadcast ds_read_b128 (whole wave
// reads one address - conflict-free), W via stride-1 b32 (2 lanes/bank - free).

template <int K>
__global__ __launch_bounds__(256) void gemm_kernel(const float* __restrict__ A, const float* __restrict__ W,
                                                   __half* __restrict__ out, int n) {
    __shared__ float Wl[K * 64];
    __shared__ float Al[32 * K];
    int tid = threadIdx.x;
    for (int f = tid; f < K * 64; f += 256) Wl[f] = W[f];
    int row0 = blockIdx.x * 32;
    const float* Ab = A + (size_t)row0 * K;
    int limit = (n - row0) * K; if (limit > 32 * K) limit = 32 * K;
    for (int f = tid * 4; f < 32 * K; f += 1024) {
        float4 v = make_float4(0.f, 0.f, 0.f, 0.f);
        if (f + 3 < limit) {
            v = *(const float4*)(Ab + f);
        } else {
            if (f + 0 < limit) v.x = Ab[f + 0];
            if (f + 1 < limit) v.y = Ab[f + 1];
            if (f + 2 < limit) v.z = Ab[f + 2];
            if (f + 3 < limit) v.w = Ab[f + 3];
        }
        *(float4*)(Al + f) = v;
    }
    __syncthreads();

    int col = tid & 63, rq = tid >> 6;
    float acc[8] = {0.f, 0.f, 0.f, 0.f, 0.f, 0.f, 0.f, 0.f};
    const float* Arow = Al + (rq * 8) * K;
    for (int k = 0; k < K; k += 4) {
        float w0 = Wl[(k + 0) * 64 + col];
        float w1 = Wl[(k + 1) * 64 + col];
        float w2 = Wl[(k + 2) * 64 + col];
        float w3 = Wl[(k + 3) * 64 + col];
#pragma unroll
        for (int r = 0; r < 8; ++r) {
            float4 av = *(const float4*)(Arow + r * K + k);
            acc[r] += av.x * w0 + av.y * w1 + av.z * w2 + av.w * w3;
        }
    }
    int r0 = row0 + rq * 8;
#pragma unroll
    for (int r = 0; r < 8; ++r)
        if (r0 + r < n) out[(size_t)(r0 + r) * 64 + col] = __float2half(acc[r]);
}

// ---------------- aggregation + bias + BN(eval) + ReLU (+classifier) ----------------
// Wave = 2 groups x 32 lanes; lane owns a half2 feature pair; each gather
// instruction fetches 2 different rows (one per group) -> 2x cache lines in
// flight per instruction slot. Unroll 4 -> 8 rows outstanding per wave.

template <bool FUSE_CLS>
__global__ __launch_bounds__(256) void agg_kernel(const __half* __restrict__ t, const float* __restrict__ dinv,
                                                  const int* __restrict__ rowptr, const int2* __restrict__ csrw,
                                                  const float* __restrict__ bias, const float* __restrict__ gamma,
                                                  const float* __restrict__ beta, const float* __restrict__ mean,
                                                  const float* __restrict__ var, float* __restrict__ out,
                                                  const float* __restrict__ cls_w, const float* __restrict__ cls_b,
                                                  int n) {
    int wave = threadIdx.x >> 6;
    int lane = threadIdx.x & 63;
    int g = lane >> 5;          // edge group 0/1
    int fl = lane & 31;         // feature-pair index (features 2*fl, 2*fl+1)
    int i = blockIdx.x * (blockDim.x >> 6) + wave;
    if (i >= n) return;

    const half2* t2 = (const half2*)t;
    float2 acc = make_float2(0.f, 0.f);

    if (g == 0) {   // self-loop counted once
        float di = dinv[i];
        float2 v = __half22float2(t2[(size_t)i * 32 + fl]);
        acc.x = di * di * v.x;
        acc.y = di * di * v.y;
    }

    int e0 = rowptr[i], e1 = rowptr[i + 1];
    int e = e0;
    for (; e + 8 <= e1; e += 8) {
        int2 a0 = csrw[e + 0 + g];
        int2 a1 = csrw[e + 2 + g];
        int2 a2 = csrw[e + 4 + g];
        int2 a3 = csrw[e + 6 + g];
        float2 v0 = __half22float2(t2[(size_t)a0.x * 32 + fl]);
        float2 v1 = __half22float2(t2[(size_t)a1.x * 32 + fl]);
        float2 v2 = __half22float2(t2[(size_t)a2.x * 32 + fl]);
        float2 v3 = __half22float2(t2[(size_t)a3.x * 32 + fl]);
        float w0 = __int_as_float(a0.y), w1 = __int_as_float(a1.y);
        float w2 = __int_as_float(a2.y), w3 = __int_as_float(a3.y);
        acc.x += w0 * v0.x + w1 * v1.x + w2 * v2.x + w3 * v3.x;
        acc.y += w0 * v0.y + w1 * v1.y + w2 * v2.y + w3 * v3.y;
    }
    for (; e + 2 <= e1; e += 2) {
        int2 a = csrw[e + g];
        float2 v = __half22float2(t2[(size_t)a.x * 32 + fl]);
        float w = __int_as_float(a.y);
        acc.x += w * v.x;
        acc.y += w * v.y;
    }
    if (e < e1 && g == 0) {     // odd last edge
        int2 a = csrw[e];
        float2 v = __half22float2(t2[(size_t)a.x * 32 + fl]);
        float w = __int_as_float(a.y);
        acc.x += w * v.x;
        acc.y += w * v.y;
    }

    // combine the two groups
    acc.x += __shfl_xor(acc.x, 32);
    acc.y += __shfl_xor(acc.y, 32);

    // bias + BN(eval) + ReLU on the feature pair
    float2 bb = ((const float2*)bias)[fl];
    float2 gg = ((const float2*)gamma)[fl];
    float2 be = ((const float2*)beta)[fl];
    float2 mm = ((const float2*)mean)[fl];
    float2 vv = ((const float2*)var)[fl];
    float sx = gg.x * rsqrtf(vv.x + EPS);
    float sy = gg.y * rsqrtf(vv.y + EPS);
    float rx = fmaxf((acc.x + bb.x - mm.x) * sx + be.x, 0.f);
    float ry = fmaxf((acc.y + bb.y - mm.y) * sy + be.y, 0.f);

    if (!FUSE_CLS) {
        if (g == 0) ((float2*)out)[(size_t)i * 32 + fl] = make_float2(rx, ry);
    } else {
        // cls_w layout [64][2]; float4 at fl covers features 2fl,2fl+1
        float4 cw = ((const float4*)cls_w)[fl];
        float c0 = rx * cw.x + ry * cw.z;
        float c1 = rx * cw.y + ry * cw.w;
        for (int off = 16; off > 0; off >>= 1) {
            c0 += __shfl_xor(c0, off);
            c1 += __shfl_xor(c1, off);
        }
        if (lane == 0) {
            out[(size_t)i * 2 + 0] = c0 + cls_b[0];
            out[(size_t)i * 2 + 1] = c1 + cls_b[1];
        }
    }
}

// ---------------- launch ----------------

extern "C" void kernel_launch(void* const* d_in, const int* in_sizes, int n_in,
                              void* d_out, int out_size, void* d_ws, size_t ws_size,
                              hipStream_t stream) {
    const float* x      = (const float*)d_in[0];
    const int*   ei     = (const int*)d_in[1];
    const float* w0     = (const float*)d_in[2];
    const float* w1     = (const float*)d_in[3];
    const float* w2     = (const float*)d_in[4];
    const float* biases = (const float*)d_in[5];
    const float* gamma  = (const float*)d_in[6];
    const float* beta   = (const float*)d_in[7];
    const float* rmean  = (const float*)d_in[8];
    const float* rvar   = (const float*)d_in[9];
    const float* cls_w  = (const float*)d_in[10];
    const float* cls_b  = (const float*)d_in[11];
    float* out = (float*)d_out;

    const int IN = 128, H = 64;
    const int N = in_sizes[0] / IN;   // 100000
    const int E = in_sizes[1] / 2;    // 1200000

    char* p = (char*)d_ws;
    auto carve = [&](size_t bytes) { void* q = (void*)p; p += (bytes + 255) & ~(size_t)255; return q; };
    float* dinv   = (float*)carve((size_t)N * 4);
    int*   count  = (int*)carve((size_t)N * 4);
    int*   rowptr = (int*)carve((size_t)(N + 1) * 4);
    int*   cursor = (int*)carve((size_t)N * 4);
    int2*  csrw   = (int2*)carve((size_t)E * 8);
    int*   bsum   = (int*)carve((size_t)1024 * 4);
    int*   boffs  = (int*)carve((size_t)1024 * 4);
    __half* tbuf  = (__half*)carve((size_t)N * H * 2);
    float* hbuf   = (float*)carve((size_t)N * H * 4);

    int nb = (N + SCAN_CHUNK - 1) / SCAN_CHUNK;   // 98 for N=100000

    hipMemsetAsync(count, 0, (size_t)N * 4, stream);
    hist_kernel<<<(E + 255) / 256, 256, 0, stream>>>(ei, E, count);
    dinv_kernel<<<(N + 255) / 256, 256, 0, stream>>>(count, dinv, N);
    scan_pass1<<<nb, 256, 0, stream>>>(count, rowptr, bsum, N);
    scan_pass2<<<1, 1024, 0, stream>>>(bsum, boffs, rowptr, nb, N);
    scan_pass3<<<nb, 256, 0, stream>>>(rowptr, cursor, boffs, N);
    scatter_kernel<<<(E + 255) / 256, 256, 0, stream>>>(ei, E, dinv, cursor, csrw);

    int gemm_grid = (N + 31) / 32;
    int agg_grid  = (N + 3) / 4;

    // layer 0
    gemm_kernel<128><<<gemm_grid, 256, 0, stream>>>(x, w0, tbuf, N);
    agg_kernel<false><<<agg_grid, 256, 0, stream>>>(tbuf, dinv, rowptr, csrw,
        biases + 0, gamma + 0, beta + 0, rmean + 0, rvar + 0, hbuf, nullptr, nullptr, N);
    // layer 1
    gemm_kernel<64><<<gemm_grid, 256, 0, stream>>>(hbuf, w1, tbuf, N);
    agg_kernel<false><<<agg_grid, 256, 0, stream>>>(tbuf, dinv, rowptr, csrw,
        biases + H, gamma + H, beta + H, rmean + H, rvar + H, hbuf, nullptr, nullptr, N);
    // layer 2 + classifier
    gemm_kernel<64><<<gemm_grid, 256, 0, stream>>>(hbuf, w2, tbuf, N);
    agg_kernel<true><<<agg_grid, 256, 0, stream>>>(tbuf, dinv, rowptr, csrw,
        biases + 2 * H, gamma + 2 * H, beta + 2 * H, rmean + 2 * H, rvar + 2 * H, out, cls_w, cls_b, N);
}